// Round 1
// baseline (60448.029 us; speedup 1.0000x reference)
//
#include <hip/hip_runtime.h>
#include <math.h>

// ---- problem constants ----
#define T_STEPS 256
#define NB      1024          // batch
#define HID     256           // H
#define N4      1025          // 4H+1
#define ACT_DIM 64
#define SN      1040          // padded fs row stride (16B-aligned rows)
#define BH      262144        // NB*HID

__device__ __forceinline__ float sigmoidf_(float x) { return 1.f / (1.f + expf(-x)); }

// ---------------------------------------------------------------------------
// Generic tiled fp32 GEMM: C[row, col<N] = act(A @ W + bias)
// Tile: 64 rows x 32 cols, 128 threads, 4x4 per thread, BK=16.
// MODE 0: A = A0[row*lda + k]
// MODE 1: cell1 gather: k<256 -> h1 ; k<512 -> z*h2 ; else xe_t   (K=768)
// MODE 2: cell2 gather: k<256 -> h2 ; else z*h1n                  (K=512)
// ACTF: 0 none, 1 relu, 2 tanh
// ---------------------------------------------------------------------------
template<int MODE, int ACTF>
__global__ __launch_bounds__(128)
void gemm_k(const float* __restrict__ A0, const float* __restrict__ A1,
            const float* __restrict__ A2, const float* __restrict__ zrow,
            const float* __restrict__ W, int ldw,
            const float* __restrict__ bias,
            float* __restrict__ C, int ldc,
            int N, int K, int lda)
{
    __shared__ __align__(16) float At[16 * 68];   // A transposed [kk][row], stride 68
    __shared__ __align__(16) float Wt[16 * 32];   // W tile [kk][col]

    const int r0  = blockIdx.y * 64;
    const int j0  = blockIdx.x * 32;
    const int tid = threadIdx.x;
    const int rq  = tid >> 3;    // 0..15 -> row group of 4
    const int jj  = tid & 7;     // 0..7  -> col group of 4

    float acc[4][4] = {};

    for (int k0 = 0; k0 < K; k0 += 16) {
        // stage A (transposed into LDS)
#pragma unroll
        for (int it = 0; it < 8; ++it) {
            int idx = it * 128 + tid;
            int r = idx >> 4, kk = idx & 15;
            int row = r0 + r, k = k0 + kk;
            float v;
            if (MODE == 0) {
                v = A0[(size_t)row * lda + k];
            } else if (MODE == 1) {
                if (k < 256)      v = A0[row * 256 + k];
                else if (k < 512) v = zrow[row] * A1[row * 256 + (k - 256)];
                else              v = A2[row * 256 + (k - 512)];
            } else {
                if (k < 256)      v = A0[row * 256 + k];
                else              v = zrow[row] * A1[row * 256 + (k - 256)];
            }
            At[kk * 68 + r] = v;
        }
        // stage W
#pragma unroll
        for (int it = 0; it < 4; ++it) {
            int idx = it * 128 + tid;
            int kk = idx >> 5, c = idx & 31;
            int col = j0 + c;
            Wt[kk * 32 + c] = (col < N) ? W[(size_t)(k0 + kk) * ldw + col] : 0.f;
        }
        __syncthreads();
#pragma unroll
        for (int kk = 0; kk < 16; ++kk) {
            float4 a4 = *reinterpret_cast<const float4*>(&At[kk * 68 + (rq << 2)]);
            float4 w4 = *reinterpret_cast<const float4*>(&Wt[(kk << 5) + (jj << 2)]);
            float a[4] = {a4.x, a4.y, a4.z, a4.w};
            float wv[4] = {w4.x, w4.y, w4.z, w4.w};
#pragma unroll
            for (int p = 0; p < 4; ++p)
#pragma unroll
                for (int q = 0; q < 4; ++q)
                    acc[p][q] = fmaf(a[p], wv[q], acc[p][q]);
        }
        __syncthreads();
    }

#pragma unroll
    for (int p = 0; p < 4; ++p) {
        int row = r0 + (rq << 2) + p;
#pragma unroll
        for (int q = 0; q < 4; ++q) {
            int col = j0 + (jj << 2) + q;
            if (col < N) {
                float v = acc[p][q];
                if (bias) v += bias[col];
                if (ACTF == 1) v = fmaxf(v, 0.f);
                else if (ACTF == 2) v = tanhf(v);
                C[(size_t)row * ldc + col] = v;
            }
        }
    }
}

// ---------------------------------------------------------------------------
// gate kernels (elementwise over [NB, HID])
// ---------------------------------------------------------------------------
__global__ __launch_bounds__(256)
void gate1_k(const float* __restrict__ fs, const float* __restrict__ c_prev,
             const float* __restrict__ noise_t,
             float* __restrict__ h_new, float* __restrict__ c_new,
             float* __restrict__ z_new)
{
    int idx = blockIdx.x * 256 + threadIdx.x;   // 0..BH-1
    int b = idx >> 8, j = idx & 255;
    const float* fr = fs + (size_t)b * SN;
    float f = sigmoidf_(fr[j]);
    float i = sigmoidf_(fr[256 + j]);
    float o = sigmoidf_(fr[512 + j]);
    float g = tanhf(fr[768 + j]);
    float c = c_prev[idx];
    float cn = f * c + i * g;
    float hn = o * tanhf(cn);
    c_new[idx] = cn;
    h_new[idx] = hn;
    if (j == 0) {
        float zh = 0.5f * (0.1f * fr[1024] + 1.f);
        zh = fminf(fmaxf(zh, 0.05f), 0.95f);
        z_new[b] = (noise_t[b] < zh) ? 1.f : 0.f;
    }
}

__global__ __launch_bounds__(256)
void gate2_k(const float* __restrict__ fs, const float* __restrict__ c_prev,
             const float* __restrict__ z1,
             float* __restrict__ h_new, float* __restrict__ c_new,
             float* __restrict__ emb_t)
{
    int idx = blockIdx.x * 256 + threadIdx.x;
    int b = idx >> 8, j = idx & 255;
    const float* fr = fs + (size_t)b * SN;
    float f = sigmoidf_(fr[j]);
    float i = sigmoidf_(fr[256 + j]);
    float o = sigmoidf_(fr[512 + j]);
    float g = tanhf(fr[768 + j]);
    float c = c_prev[idx];
    float z = z1[b];
    float cn = (1.f - z) * c + z * (f * c + i * g);
    float hn = o * tanhf(cn);
    c_new[idx] = cn;
    h_new[idx] = hn;
    emb_t[idx] = hn;
}

__global__ __launch_bounds__(256)
void init_k(float* h1, float* c1, float* h2, float* c2, float* z1)
{
    int i = blockIdx.x * 256 + threadIdx.x;
    if (i < BH) { h1[i] = 0.f; c1[i] = 0.f; h2[i] = 0.f; c2[i] = 0.f; }
    if (i < NB) z1[i] = 1.f;
}

// ---------------------------------------------------------------------------
extern "C" void kernel_launch(void* const* d_in, const int* in_sizes, int n_in,
                              void* d_out, int out_size, void* d_ws, size_t ws_size,
                              hipStream_t stream)
{
    const float* x     = (const float*)d_in[0];
    const float* n1    = (const float*)d_in[1];
    // d_in[2] = noise2 (unused in forward output)
    const float* We1   = (const float*)d_in[3];
    const float* be1   = (const float*)d_in[4];
    const float* We2   = (const float*)d_in[5];
    const float* be2   = (const float*)d_in[6];
    const float* U11_1 = (const float*)d_in[7];
    const float* U21_1 = (const float*)d_in[8];
    const float* W01_1 = (const float*)d_in[9];
    const float* b1    = (const float*)d_in[10];
    const float* U11_2 = (const float*)d_in[11];
    const float* W01_2 = (const float*)d_in[12];
    const float* b2    = (const float*)d_in[13];
    const float* Wh    = (const float*)d_in[14];
    const float* bh    = (const float*)d_in[15];
    const float* Wp    = (const float*)d_in[16];
    const float* bp    = (const float*)d_in[17];
    float* out = (float*)d_out;

    // ---- workspace layout (floats) ----
    float* w = (float*)d_ws;
    size_t off = 0;
    auto alloc = [&](size_t n) { float* p = w + off; off += (n + 63) & ~(size_t)63; return p; };
    float* bufA = alloc((size_t)T_STEPS * BH);   // xe1, then emb
    float* bufB = alloc((size_t)T_STEPS * BH);   // xe,  then hid
    float* wc1  = alloc((size_t)768 * 1025);     // [W01_1; U21_1; U11_1]
    float* wc2  = alloc((size_t)512 * 1025);     // [W01_2; U11_2]
    float* fs1  = alloc((size_t)NB * SN);
    float* fs2  = alloc((size_t)NB * SN);
    float* sb   = alloc((size_t)8 * BH + 2 * NB);
    float* h1b[2] = { sb + 0 * BH, sb + 1 * BH };
    float* c1b[2] = { sb + 2 * BH, sb + 3 * BH };
    float* h2b[2] = { sb + 4 * BH, sb + 5 * BH };
    float* c2b[2] = { sb + 6 * BH, sb + 7 * BH };
    float* z1b[2] = { sb + 8 * BH, sb + 8 * BH + NB };
    if (ws_size < off * sizeof(float)) return;   // diagnostic: leaves zeros in d_out

    // ---- concat step weights (row blocks match gather order) ----
    size_t wblk = (size_t)256 * 1025 * sizeof(float);
    hipMemcpyAsync(wc1,              W01_1, wblk, hipMemcpyDeviceToDevice, stream);
    hipMemcpyAsync(wc1 + 256 * 1025, U21_1, wblk, hipMemcpyDeviceToDevice, stream);
    hipMemcpyAsync(wc1 + 512 * 1025, U11_1, wblk, hipMemcpyDeviceToDevice, stream);
    hipMemcpyAsync(wc2,              W01_2, wblk, hipMemcpyDeviceToDevice, stream);
    hipMemcpyAsync(wc2 + 256 * 1025, U11_2, wblk, hipMemcpyDeviceToDevice, stream);

    init_k<<<dim3(BH / 256), 256, 0, stream>>>(h1b[0], c1b[0], h2b[0], c2b[0], z1b[0]);

    // ---- encoder: xe = relu(relu(x@We1+be1)@We2+be2) ----
    gemm_k<0, 1><<<dim3(8, 4096), 128, 0, stream>>>(
        x, nullptr, nullptr, nullptr, We1, 256, be1, bufA, 256, 256, 256, 256);
    gemm_k<0, 1><<<dim3(8, 4096), 128, 0, stream>>>(
        bufA, nullptr, nullptr, nullptr, We2, 256, be2, bufB, 256, 256, 256, 256);

    // ---- recurrence ----
    int cur = 0;
    for (int t = 0; t < T_STEPS; ++t) {
        const float* xe_t  = bufB + (size_t)t * BH;
        float*       emb_t = bufA + (size_t)t * BH;
        int nxt = cur ^ 1;
        // fs1 = [h1, z1*h2, xe_t] @ wc1 + b1
        gemm_k<1, 0><<<dim3(33, 16), 128, 0, stream>>>(
            h1b[cur], h2b[cur], xe_t, z1b[cur], wc1, 1025, b1, fs1, SN, 1025, 768, 0);
        gate1_k<<<dim3(BH / 256), 256, 0, stream>>>(
            fs1, c1b[cur], n1 + (size_t)t * NB, h1b[nxt], c1b[nxt], z1b[nxt]);
        // fs2 = [h2, z1n*h1n] @ wc2 + b2
        gemm_k<2, 0><<<dim3(33, 16), 128, 0, stream>>>(
            h2b[cur], h1b[nxt], nullptr, z1b[nxt], wc2, 1025, b2, fs2, SN, 1025, 512, 0);
        gate2_k<<<dim3(BH / 256), 256, 0, stream>>>(
            fs2, c2b[cur], z1b[nxt], h2b[nxt], c2b[nxt], emb_t);
        cur = nxt;
    }

    // ---- head: out = tanh(relu(emb@Wh+bh)@Wp+bp) ----
    gemm_k<0, 1><<<dim3(8, 4096), 128, 0, stream>>>(
        bufA, nullptr, nullptr, nullptr, Wh, 256, bh, bufB, 256, 256, 256, 256);
    gemm_k<0, 2><<<dim3(2, 4096), 128, 0, stream>>>(
        bufB, nullptr, nullptr, nullptr, Wp, 64, bp, out, 64, 64, 256, 256);
}

// Round 2
// 12137.229 us; speedup vs baseline: 4.9804x; 4.9804x over previous
//
#include <hip/hip_runtime.h>
#include <math.h>

typedef __attribute__((ext_vector_type(8))) _Float16 half8;
typedef __attribute__((ext_vector_type(4))) _Float16 half4;
typedef __attribute__((ext_vector_type(4))) float    f32x4;

#define NSTEP 256
#define NB    1024
#define HID   256
#define BH    262144          // NB*HID
#define LK    40              // padded LDS k-stride in f16 units (80B -> 2-way banks only)
#define INV2K 4.8828125e-4f   // 1/2048

__device__ __forceinline__ float sigf(float x){ return 1.f/(1.f+expf(-x)); }

// ---------------------------------------------------------------------------
// Weight pre-split (transpose + fp16 hi/lo): out[n][k] from up to 3 stacked
// sources s0/s1/s2 (row-major [k][ldn]), k-boundaries kb1/kb2.
// ---------------------------------------------------------------------------
__global__ __launch_bounds__(256)
void wsplit_k(const float* __restrict__ s0, const float* __restrict__ s1,
              const float* __restrict__ s2, int K, int N, int ldn,
              int kb1, int kb2, _Float16* __restrict__ oh, _Float16* __restrict__ ol)
{
    int idx = blockIdx.x*256 + threadIdx.x;
    if (idx >= N*K) return;
    int n = idx / K, k = idx - n*K;
    const float* s = (k < kb1) ? &s0[(size_t)k*ldn]
                   : (k < kb2) ? &s1[(size_t)(k-kb1)*ldn]
                               : &s2[(size_t)(k-kb2)*ldn];
    float v = s[n];
    _Float16 h = (_Float16)v;
    oh[idx] = h;
    ol[idx] = (_Float16)((v - (float)h)*2048.f);
}

// extract z-column (col 1024) weights of cell1 into contiguous fp32 [768]
__global__ void wz_k(const float* __restrict__ W01, const float* __restrict__ U21,
                     const float* __restrict__ U11, float* __restrict__ wz)
{
    int k = blockIdx.x*256 + threadIdx.x;
    if (k >= 768) return;
    wz[k] = (k < 256) ? W01[(size_t)k*1025 + 1024]
          : (k < 512) ? U21[(size_t)(k-256)*1025 + 1024]
                      : U11[(size_t)(k-512)*1025 + 1024];
}

__global__ void init_k(float* __restrict__ sb)
{
    size_t i = (size_t)blockIdx.x*256 + threadIdx.x;
    size_t n0 = 8ull*BH;
    if (i < n0) sb[i] = 0.f;
    else if (i < n0 + NB) sb[i] = 1.f;   // z1 init = 1
}

// ---------------------------------------------------------------------------
// Fused HM-LSTM cell step: split-fp16 MFMA GEMM + gate epilogue.
// Block: 256 thr (4 waves), wave w = gate w. Tile: 32 batch-rows x 32 j-cols,
// each wave computes fs[32 x 32] of its gate (cols w*256 + j0 + [0,32)).
// CELL=1: A = [h1 | z1*h2 | xe], K=768, outputs h1n,c1n,z1n (z col in fp32 VALU)
// CELL=2: A = [h2 | z1n*h1n],    K=512, outputs h2n,c2n,emb
// ---------------------------------------------------------------------------
template<int CELL>
__global__ __launch_bounds__(256)
void cell_k(const float* __restrict__ A0, const float* __restrict__ A1,
            const float* __restrict__ A2, const float* __restrict__ zrow,
            const _Float16* __restrict__ Wth, const _Float16* __restrict__ Wtl,
            const float* __restrict__ bias, const float* __restrict__ wzf,
            const float* __restrict__ noise, const float* __restrict__ c_prev,
            float* __restrict__ h_out, float* __restrict__ c_out,
            float* __restrict__ z_out, float* __restrict__ emb_out)
{
    constexpr int K = (CELL == 1) ? 768 : 512;
    __shared__ __align__(16) unsigned char smem[25600];
    _Float16* Ah = (_Float16*)smem;                 // [32][LK]
    _Float16* Al = (_Float16*)(smem + 2560);        // [32][LK]
    _Float16* Wh = (_Float16*)(smem + 5120);        // [4*32][LK]
    _Float16* Wl = (_Float16*)(smem + 15360);       // [4*32][LK]
    float*    ex = (float*)(smem + 5120);           // epilogue overlay [4][32][32] f32

    const int tid  = threadIdx.x;
    const int wid  = tid >> 6;           // gate index
    const int lane = tid & 63;
    const int j0   = blockIdx.x * 32;
    const int b0   = blockIdx.y * 32;
    const int srow = tid >> 3;           // 0..31 staging row
    const int skk  = (tid & 7) << 2;     // staging k offset (0,4,..28)
    const int lr   = lane & 15;
    const int kq   = (lane >> 4) << 3;   // frag k offset: 0,8,16,24

    f32x4 accm[2][2], accx[2][2];
#pragma unroll
    for (int r=0;r<2;++r)
#pragma unroll
        for (int c=0;c<2;++c){ accm[r][c]=(f32x4)0.f; accx[r][c]=(f32x4)0.f; }
    float zpart = 0.f;
    const bool do_z = (CELL==1) && (j0==0);

    for (int k0 = 0; k0 < K; k0 += 32) {
        // ---- stage A tile (gather + split) ----
        {
            int kg = k0 + skk;
            const float* src; float zs = 1.f;
            if (CELL == 1) {
                if (kg < 256)       src = &A0[(size_t)(b0+srow)*HID + kg];
                else if (kg < 512) { src = &A1[(size_t)(b0+srow)*HID + kg-256]; zs = zrow[b0+srow]; }
                else                src = &A2[(size_t)(b0+srow)*HID + kg-512];
            } else {
                if (kg < 256)       src = &A0[(size_t)(b0+srow)*HID + kg];
                else               { src = &A1[(size_t)(b0+srow)*HID + kg-256]; zs = zrow[b0+srow]; }
            }
            float4 av = *(const float4*)src;
            av.x *= zs; av.y *= zs; av.z *= zs; av.w *= zs;
            half4 hv, lv;
            hv.x=(_Float16)av.x; lv.x=(_Float16)((av.x-(float)hv.x)*2048.f);
            hv.y=(_Float16)av.y; lv.y=(_Float16)((av.y-(float)hv.y)*2048.f);
            hv.z=(_Float16)av.z; lv.z=(_Float16)((av.z-(float)hv.z)*2048.f);
            hv.w=(_Float16)av.w; lv.w=(_Float16)((av.w-(float)hv.w)*2048.f);
            *(half4*)&Ah[srow*LK + skk] = hv;
            *(half4*)&Al[srow*LK + skk] = lv;
        }
        // ---- stage W tile: wave w stages its gate's 32 cols ----
#pragma unroll
        for (int sub=0; sub<2; ++sub) {
            int col = sub*16 + (lane>>2);
            int seg = (lane&3)*8;
            size_t g = (size_t)(wid*256 + j0 + col)*K + k0 + seg;
            *(half8*)&Wh[(wid*32+col)*LK + seg] = *(const half8*)&Wth[g];
            *(half8*)&Wl[(wid*32+col)*LK + seg] = *(const half8*)&Wtl[g];
        }
        __syncthreads();
        // ---- z-column partials (exact fp32 path) ----
        if (do_z) {
#pragma unroll
            for (int j=0;j<4;++j) {
                float a = (float)Ah[srow*LK+skk+j] + (float)Al[srow*LK+skk+j]*INV2K;
                zpart = fmaf(a, wzf[k0+skk+j], zpart);
            }
        }
        // ---- MFMA: main (hi*hi) + cross (hi*lo + lo*hi) ----
        {
            half8 ah[2], al[2];
#pragma unroll
            for (int r=0;r<2;++r) {
                ah[r] = *(half8*)&Ah[(r*16+lr)*LK + kq];
                al[r] = *(half8*)&Al[(r*16+lr)*LK + kq];
            }
#pragma unroll
            for (int c=0;c<2;++c) {
                half8 bh = *(half8*)&Wh[(wid*32 + c*16 + lr)*LK + kq];
                half8 bl = *(half8*)&Wl[(wid*32 + c*16 + lr)*LK + kq];
#pragma unroll
                for (int r=0;r<2;++r) {
                    accm[r][c] = __builtin_amdgcn_mfma_f32_16x16x32_f16(ah[r], bh, accm[r][c], 0,0,0);
                    accx[r][c] = __builtin_amdgcn_mfma_f32_16x16x32_f16(ah[r], bl, accx[r][c], 0,0,0);
                    accx[r][c] = __builtin_amdgcn_mfma_f32_16x16x32_f16(al[r], bh, accx[r][c], 0,0,0);
                }
            }
        }
        __syncthreads();
    }

    // ---- z finalize: reduce 8 staging threads per row ----
    if (do_z) {
        float s = zpart;
        s += __shfl_xor(s, 1);
        s += __shfl_xor(s, 2);
        s += __shfl_xor(s, 4);
        if ((lane & 7) == 0) {
            int row = wid*8 + (lane >> 3);
            float fsz = s + bias[4*HID];
            float zh = (0.1f*fsz + 1.f)*0.5f;
            zh = fminf(fmaxf(zh, 0.05f), 0.95f);
            z_out[b0+row] = (noise[b0+row] < zh) ? 1.f : 0.f;
        }
    }

    // ---- activations -> LDS exchange (overlays W; protected by last barrier) ----
#pragma unroll
    for (int r=0;r<2;++r)
#pragma unroll
        for (int c=0;c<2;++c)
#pragma unroll
            for (int q=0;q<4;++q) {
                int row = r*16 + ((lane>>4)<<2) + q;   // C layout: row=(lane>>4)*4+reg
                int col = c*16 + lr;                   //           col=lane&15
                float v = accm[r][c][q] + accx[r][c][q]*INV2K + bias[wid*256 + j0 + col];
                v = (wid < 3) ? sigf(v) : tanhf(v);
                ex[wid*1024 + row*32 + col] = v;
            }
    __syncthreads();

    // ---- recombine gates -> state update ----
    {
        float4 f = *(float4*)&ex[0*1024 + srow*32 + skk];
        float4 i = *(float4*)&ex[1*1024 + srow*32 + skk];
        float4 o = *(float4*)&ex[2*1024 + srow*32 + skk];
        float4 g = *(float4*)&ex[3*1024 + srow*32 + skk];
        size_t gi = (size_t)(b0+srow)*HID + j0 + skk;
        float4 co = *(const float4*)&c_prev[gi];
        float4 cn, hn;
        if (CELL == 1) {
            cn.x = f.x*co.x + i.x*g.x; cn.y = f.y*co.y + i.y*g.y;
            cn.z = f.z*co.z + i.z*g.z; cn.w = f.w*co.w + i.w*g.w;
        } else {
            float z = zrow[b0+srow];
            cn.x = (1.f-z)*co.x + z*(f.x*co.x + i.x*g.x);
            cn.y = (1.f-z)*co.y + z*(f.y*co.y + i.y*g.y);
            cn.z = (1.f-z)*co.z + z*(f.z*co.z + i.z*g.z);
            cn.w = (1.f-z)*co.w + z*(f.w*co.w + i.w*g.w);
        }
        hn.x = o.x*tanhf(cn.x); hn.y = o.y*tanhf(cn.y);
        hn.z = o.z*tanhf(cn.z); hn.w = o.w*tanhf(cn.w);
        *(float4*)&c_out[gi] = cn;
        *(float4*)&h_out[gi] = hn;
        if (CELL == 2) *(float4*)&emb_out[gi] = hn;
    }
}

// ---------------------------------------------------------------------------
// Big parallel GEMM (encoder/head): C[M x BN] = act(A[M x 256] @ W + bias)
// split-fp16 MFMA. Block: 32 rows x BN cols, 4 waves each own BN/4 cols.
// ---------------------------------------------------------------------------
template<int BN, int ACTF>   // ACTF: 1 relu, 2 tanh
__global__ __launch_bounds__(256)
void bgemm_k(const float* __restrict__ A, const _Float16* __restrict__ Wth,
             const _Float16* __restrict__ Wtl, const float* __restrict__ bias,
             float* __restrict__ C)
{
    constexpr int K  = 256;
    constexpr int CF = BN/64;                 // colfrags per wave
    __shared__ __align__(16) unsigned char smem[5120 + 4*BN*LK];
    _Float16* Ah = (_Float16*)smem;
    _Float16* Al = (_Float16*)(smem + 2560);
    _Float16* Bh = (_Float16*)(smem + 5120);
    _Float16* Bl = (_Float16*)(smem + 5120 + 2*BN*LK);

    const int tid  = threadIdx.x;
    const int wid  = tid >> 6;
    const int lane = tid & 63;
    const size_t r0 = (size_t)blockIdx.x * 32;
    const int srow = tid >> 3;
    const int skk  = (tid & 7) << 2;
    const int lr   = lane & 15;
    const int kq   = (lane >> 4) << 3;

    f32x4 accm[2][CF], accx[2][CF];
#pragma unroll
    for (int r=0;r<2;++r)
#pragma unroll
        for (int c=0;c<CF;++c){ accm[r][c]=(f32x4)0.f; accx[r][c]=(f32x4)0.f; }

    for (int k0=0; k0<K; k0+=32) {
        {
            float4 av = *(const float4*)&A[(r0+srow)*K + k0 + skk];
            half4 hv, lv;
            hv.x=(_Float16)av.x; lv.x=(_Float16)((av.x-(float)hv.x)*2048.f);
            hv.y=(_Float16)av.y; lv.y=(_Float16)((av.y-(float)hv.y)*2048.f);
            hv.z=(_Float16)av.z; lv.z=(_Float16)((av.z-(float)hv.z)*2048.f);
            hv.w=(_Float16)av.w; lv.w=(_Float16)((av.w-(float)hv.w)*2048.f);
            *(half4*)&Ah[srow*LK + skk] = hv;
            *(half4*)&Al[srow*LK + skk] = lv;
        }
#pragma unroll
        for (int sub=0; sub<BN/64; ++sub) {
            int col = sub*64 + (tid>>2);
            int seg = (tid&3)*8;
            size_t g = (size_t)col*K + k0 + seg;
            *(half8*)&Bh[col*LK + seg] = *(const half8*)&Wth[g];
            *(half8*)&Bl[col*LK + seg] = *(const half8*)&Wtl[g];
        }
        __syncthreads();
        {
            half8 ah[2], al[2];
#pragma unroll
            for (int r=0;r<2;++r) {
                ah[r] = *(half8*)&Ah[(r*16+lr)*LK + kq];
                al[r] = *(half8*)&Al[(r*16+lr)*LK + kq];
            }
#pragma unroll
            for (int c=0;c<CF;++c) {
                int bcol = wid*(BN/4) + c*16 + lr;
                half8 bh = *(half8*)&Bh[bcol*LK + kq];
                half8 bl = *(half8*)&Bl[bcol*LK + kq];
#pragma unroll
                for (int r=0;r<2;++r) {
                    accm[r][c] = __builtin_amdgcn_mfma_f32_16x16x32_f16(ah[r], bh, accm[r][c], 0,0,0);
                    accx[r][c] = __builtin_amdgcn_mfma_f32_16x16x32_f16(ah[r], bl, accx[r][c], 0,0,0);
                    accx[r][c] = __builtin_amdgcn_mfma_f32_16x16x32_f16(al[r], bh, accx[r][c], 0,0,0);
                }
            }
        }
        __syncthreads();
    }
#pragma unroll
    for (int r=0;r<2;++r)
#pragma unroll
        for (int c=0;c<CF;++c)
#pragma unroll
            for (int q=0;q<4;++q) {
                size_t row = r0 + r*16 + ((lane>>4)<<2) + q;
                int col = wid*(BN/4) + c*16 + lr;
                float v = accm[r][c][q] + accx[r][c][q]*INV2K + bias[col];
                if (ACTF == 1) v = fmaxf(v, 0.f);
                else           v = tanhf(v);
                C[row*BN + col] = v;
            }
}

// ---------------------------------------------------------------------------
extern "C" void kernel_launch(void* const* d_in, const int* in_sizes, int n_in,
                              void* d_out, int out_size, void* d_ws, size_t ws_size,
                              hipStream_t stream)
{
    const float* x     = (const float*)d_in[0];
    const float* n1    = (const float*)d_in[1];
    const float* We1   = (const float*)d_in[3];
    const float* be1   = (const float*)d_in[4];
    const float* We2   = (const float*)d_in[5];
    const float* be2   = (const float*)d_in[6];
    const float* U11_1 = (const float*)d_in[7];
    const float* U21_1 = (const float*)d_in[8];
    const float* W01_1 = (const float*)d_in[9];
    const float* b1    = (const float*)d_in[10];
    const float* U11_2 = (const float*)d_in[11];
    const float* W01_2 = (const float*)d_in[12];
    const float* b2    = (const float*)d_in[13];
    const float* Wh    = (const float*)d_in[14];
    const float* bh    = (const float*)d_in[15];
    const float* Wp    = (const float*)d_in[16];
    const float* bp    = (const float*)d_in[17];
    float* out = (float*)d_out;

    // ---- workspace carve (bytes) ----
    char* p = (char*)d_ws;
    auto alloc = [&](size_t bytes){ char* q = p; p += (bytes + 255) & ~(size_t)255; return q; };
    float*    bufA = (float*)alloc((size_t)NSTEP*BH*4);   // xe1 -> emb
    float*    bufB = (float*)alloc((size_t)NSTEP*BH*4);   // xe  -> hid
    _Float16* Wt1h = (_Float16*)alloc((size_t)1024*768*2);
    _Float16* Wt1l = (_Float16*)alloc((size_t)1024*768*2);
    _Float16* Wt2h = (_Float16*)alloc((size_t)1024*512*2);
    _Float16* Wt2l = (_Float16*)alloc((size_t)1024*512*2);
    _Float16* We1h = (_Float16*)alloc(256*256*2);
    _Float16* We1l = (_Float16*)alloc(256*256*2);
    _Float16* We2h = (_Float16*)alloc(256*256*2);
    _Float16* We2l = (_Float16*)alloc(256*256*2);
    _Float16* Whh  = (_Float16*)alloc(256*256*2);
    _Float16* Whl  = (_Float16*)alloc(256*256*2);
    _Float16* Wph  = (_Float16*)alloc(64*256*2);
    _Float16* Wpl  = (_Float16*)alloc(64*256*2);
    float*    wz1  = (float*)alloc(768*4);
    float*    sb   = (float*)alloc(((size_t)8*BH + 2*NB)*4);
    float* h1b[2] = { sb + 0*(size_t)BH, sb + 1*(size_t)BH };
    float* c1b[2] = { sb + 2*(size_t)BH, sb + 3*(size_t)BH };
    float* h2b[2] = { sb + 4*(size_t)BH, sb + 5*(size_t)BH };
    float* c2b[2] = { sb + 6*(size_t)BH, sb + 7*(size_t)BH };
    float* z1b[2] = { sb + 8*(size_t)BH, sb + 8*(size_t)BH + NB };
    if (ws_size < (size_t)(p - (char*)d_ws)) return;

    // ---- one-time prep (idempotent, runs every call) ----
    wsplit_k<<<dim3((1024*768+255)/256), 256, 0, stream>>>(
        W01_1, U21_1, U11_1, 768, 1024, 1025, 256, 512, Wt1h, Wt1l);
    wsplit_k<<<dim3((1024*512+255)/256), 256, 0, stream>>>(
        W01_2, U11_2, nullptr, 512, 1024, 1025, 256, 512, Wt2h, Wt2l);
    wsplit_k<<<dim3((256*256+255)/256), 256, 0, stream>>>(
        We1, nullptr, nullptr, 256, 256, 256, 256, 256, We1h, We1l);
    wsplit_k<<<dim3((256*256+255)/256), 256, 0, stream>>>(
        We2, nullptr, nullptr, 256, 256, 256, 256, 256, We2h, We2l);
    wsplit_k<<<dim3((256*256+255)/256), 256, 0, stream>>>(
        Wh, nullptr, nullptr, 256, 256, 256, 256, 256, Whh, Whl);
    wsplit_k<<<dim3((64*256+255)/256), 256, 0, stream>>>(
        Wp, nullptr, nullptr, 256, 64, 64, 256, 256, Wph, Wpl);
    wz_k<<<dim3(3), 256, 0, stream>>>(W01_1, U21_1, U11_1, wz1);
    init_k<<<dim3((8*BH + NB + 255)/256), 256, 0, stream>>>(sb);

    // ---- encoder ----
    bgemm_k<256,1><<<dim3(NSTEP*NB/32), 256, 0, stream>>>(x,    We1h, We1l, be1, bufA);
    bgemm_k<256,1><<<dim3(NSTEP*NB/32), 256, 0, stream>>>(bufA, We2h, We2l, be2, bufB);

    // ---- recurrence ----
    int cur = 0;
    for (int t = 0; t < NSTEP; ++t) {
        int nxt = cur ^ 1;
        const float* xe_t  = bufB + (size_t)t*BH;
        float*       emb_t = bufA + (size_t)t*BH;
        cell_k<1><<<dim3(8,32), 256, 0, stream>>>(
            h1b[cur], h2b[cur], xe_t, z1b[cur], Wt1h, Wt1l, b1, wz1,
            n1 + (size_t)t*NB, c1b[cur], h1b[nxt], c1b[nxt], z1b[nxt], nullptr);
        cell_k<2><<<dim3(8,32), 256, 0, stream>>>(
            h2b[cur], h1b[nxt], nullptr, z1b[nxt], Wt2h, Wt2l, b2, nullptr,
            nullptr, c2b[cur], h2b[nxt], c2b[nxt], nullptr, emb_t);
        cur = nxt;
    }

    // ---- head ----
    bgemm_k<256,1><<<dim3(NSTEP*NB/32), 256, 0, stream>>>(bufA, Whh, Whl, bh, bufB);
    bgemm_k<64,2><<<dim3(NSTEP*NB/32), 256, 0, stream>>>(bufB, Wph, Wpl, bp, out);
}